// Round 2
// baseline (1532.259 us; speedup 1.0000x reference)
//
#include <hip/hip_runtime.h>
#include <math.h>

#define M_EDGES 50000

// xor swizzle at float4 granularity: staging writes (fixed c, varying k) spread
// across 8 bank groups (2 lanes/bank = free); reads stay contiguous float4.
__device__ __forceinline__ int swz(int k) { return ((k >> 2) & 7) << 2; }

// ---------------- degree counting ----------------
__global__ void count_kernel(const int* __restrict__ pair_e, const int* __restrict__ pair_v,
                             int* __restrict__ cnt_e, int* __restrict__ cnt_v, int P) {
  int p = blockIdx.x * blockDim.x + threadIdx.x;
  if (p >= P) return;
  atomicAdd(&cnt_e[pair_e[p]], 1);
  atomicAdd(&cnt_v[pair_v[p]], 1);
}

// exclusive scan, single block of 1024 threads; also emits 1/max(c,1) and 1/sqrt(max(c,1))
__global__ void scan_kernel(const int* __restrict__ cnt, int* __restrict__ off,
                            float* __restrict__ inv1, float* __restrict__ inv2, int n) {
  __shared__ int sh[1024];
  int carry = 0;
  for (int base = 0; base < n; base += 1024) {
    int i = base + (int)threadIdx.x;
    int x = (i < n) ? cnt[i] : 0;
    sh[threadIdx.x] = x;
    __syncthreads();
    for (int ofs = 1; ofs < 1024; ofs <<= 1) {
      int v = (threadIdx.x >= (unsigned)ofs) ? sh[threadIdx.x - ofs] : 0;
      __syncthreads();
      sh[threadIdx.x] += v;
      __syncthreads();
    }
    if (i < n) {
      off[i] = carry + sh[threadIdx.x] - x;
      float m = (float)(x > 1 ? x : 1);
      if (inv1) inv1[i] = 1.0f / m;
      if (inv2) inv2[i] = 1.0f / sqrtf(m);
    }
    carry += sh[1023];
    __syncthreads();
  }
  if (threadIdx.x == 0) off[n] = carry;
}

// ---------------- GEMM: H = X @ W^T + b, fused s = H.w_src, d = H.w_dst ----------------
// fp32 in/out. LDS: 32 KB (W half-K, swizzled) + 16 KB (X tile) = 48 KB.
__global__ __launch_bounds__(256) void gemm_kernel(
    const float* __restrict__ X, const float* __restrict__ W,
    const float* __restrict__ bias, const float* __restrict__ wsrc,
    const float* __restrict__ wdst,
    float* __restrict__ H, float* __restrict__ s_out, float* __restrict__ d_out,
    int N) {
  __shared__ float lw[64 * 128];   // lw[kk*128 + (c ^ swz(kk))] = W[c][half*64+kk]
  __shared__ float lx[32 * 128];   // lx[r*128 + k]
  const int tid = threadIdx.x;
  const int row0 = blockIdx.x * 32;

  // stage X tile once: 32 rows x 128 k, float4 per thread x 4
  for (int g = tid; g < 32 * 32; g += 256) {
    const int r = g >> 5;
    const int k4 = (g & 31) << 2;
    int rr = row0 + r;
    if (rr >= N) rr = N - 1;
    const float4 v = *(const float4*)(X + (size_t)rr * 128 + k4);
    *(float4*)(lx + r * 128 + k4) = v;
  }

  const int tx = tid & 31;
  const int ty = tid >> 5;
  const int c0 = tx << 2;
  const int r0 = ty << 2;
  float acc[4][4] = {};

  for (int half = 0; half < 2; ++half) {
    __syncthreads();  // lx ready (iter 0) / lw safe to overwrite (iter 1)
    // stage W half-K: c in [0,128), kk in [0,64)
    for (int g = tid; g < 128 * 16; g += 256) {
      const int c = g >> 4;
      const int kk4 = (g & 15) << 2;            // 0..60 step 4
      const float4 v = *(const float4*)(W + (size_t)c * 128 + half * 64 + kk4);
      const int s = swz(kk4);                   // constant over kk4..kk4+3
      lw[(kk4 + 0) * 128 + (c ^ s)] = v.x;
      lw[(kk4 + 1) * 128 + (c ^ s)] = v.y;
      lw[(kk4 + 2) * 128 + (c ^ s)] = v.z;
      lw[(kk4 + 3) * 128 + (c ^ s)] = v.w;
    }
    __syncthreads();
#pragma unroll 8
    for (int kk = 0; kk < 64; ++kk) {
      const int k = half * 64 + kk;
      const float4 wv = *(const float4*)(lw + kk * 128 + (c0 ^ swz(kk)));
      const float x0 = lx[(r0 + 0) * 128 + k];
      const float x1 = lx[(r0 + 1) * 128 + k];
      const float x2 = lx[(r0 + 2) * 128 + k];
      const float x3 = lx[(r0 + 3) * 128 + k];
      acc[0][0] += x0 * wv.x; acc[0][1] += x0 * wv.y; acc[0][2] += x0 * wv.z; acc[0][3] += x0 * wv.w;
      acc[1][0] += x1 * wv.x; acc[1][1] += x1 * wv.y; acc[1][2] += x1 * wv.z; acc[1][3] += x1 * wv.w;
      acc[2][0] += x2 * wv.x; acc[2][1] += x2 * wv.y; acc[2][2] += x2 * wv.z; acc[2][3] += x2 * wv.w;
      acc[3][0] += x3 * wv.x; acc[3][1] += x3 * wv.y; acc[3][2] += x3 * wv.z; acc[3][3] += x3 * wv.w;
    }
  }

  const float4 bv = *(const float4*)(bias + c0);
  const float4 sv = *(const float4*)(wsrc + c0);
  const float4 dv = *(const float4*)(wdst + c0);

#pragma unroll
  for (int r = 0; r < 4; ++r) {
    const int row = row0 + r0 + r;
    float4 h;
    h.x = acc[r][0] + bv.x; h.y = acc[r][1] + bv.y;
    h.z = acc[r][2] + bv.z; h.w = acc[r][3] + bv.w;
    float ps = h.x * sv.x + h.y * sv.y + h.z * sv.z + h.w * sv.w;
    float pd = h.x * dv.x + h.y * dv.y + h.z * dv.z + h.w * dv.w;
#pragma unroll
    for (int m = 16; m >= 1; m >>= 1) {  // reduce over the 32 tx lanes (bits 0..4)
      ps += __shfl_xor(ps, m, 64);
      pd += __shfl_xor(pd, m, 64);
    }
    if (row < N) {
      *(float4*)(H + (size_t)row * 128 + c0) = h;
      if (tx == 0) { s_out[row] = ps; d_out[row] = pd; }
    }
  }
}

// ---------------- CSR fill (counting sort) + per-slot attention weight ----------------
// es = exp(clip(leaky_relu(s[src]+d[v], 0.2), 0.001, 5)); no max-subtract needed
// since scores are clipped to [0.001, 5] (exp <= 148.4, fp32-safe; analytically identical).
__global__ void fill_kernel(const int* __restrict__ pair_e, const int* __restrict__ pair_v,
                            const int* __restrict__ src_v,
                            const int* __restrict__ edge_off, const int* __restrict__ vtx_off,
                            int* __restrict__ cur_e, int* __restrict__ cur_v,
                            int* __restrict__ edge_vtx, int* __restrict__ vtx_edge,
                            float* __restrict__ vtx_score,
                            const float* __restrict__ svec, const float* __restrict__ dvec,
                            int P) {
  int p = blockIdx.x * blockDim.x + threadIdx.x;
  if (p >= P) return;
  int e = pair_e[p], v = pair_v[p];
  int ie = edge_off[e] + atomicAdd(&cur_e[e], 1);
  edge_vtx[ie] = v;
  int iv = vtx_off[v] + atomicAdd(&cur_v[v], 1);
  vtx_edge[iv] = e;
  float sc = svec[src_v[p]] + dvec[v];
  sc = sc > 0.f ? sc : 0.2f * sc;           // leaky_relu(0.2)
  sc = fminf(fmaxf(sc, 0.001f), 5.0f);      // clip
  vtx_score[iv] = __expf(sc);
}

// ---------------- generic segment gather-reduce (wave per segment) ----------------
// dst[seg] = post_scale[seg] * sum_i pre_scale[lst[i]] * src[lst[i]]; final: ELU.
__global__ __launch_bounds__(256) void seg_pass_kernel(
    const float* __restrict__ src, float* __restrict__ dst,
    const int* __restrict__ off, const int* __restrict__ lst,
    const float* __restrict__ pre_scale, const float* __restrict__ post_scale,
    int nseg, int final_mode) {
  const int seg = blockIdx.x * 4 + ((int)threadIdx.x >> 6);
  const int lane = (int)threadIdx.x & 63;
  if (seg >= nseg) return;
  const int beg = off[seg];
  const int end = off[seg + 1];
  const int co = lane << 1;
  float ax0 = 0.f, ay0 = 0.f, ax1 = 0.f, ay1 = 0.f;
  int i = beg;
  for (; i + 2 <= end; i += 2) {
    const int j0 = lst[i];
    const int j1 = lst[i + 1];
    const float2 r0 = *(const float2*)(src + (size_t)j0 * 128 + co);
    const float2 r1 = *(const float2*)(src + (size_t)j1 * 128 + co);
    const float p0 = pre_scale ? pre_scale[j0] : 1.0f;
    const float p1 = pre_scale ? pre_scale[j1] : 1.0f;
    ax0 += r0.x * p0; ay0 += r0.y * p0;
    ax1 += r1.x * p1; ay1 += r1.y * p1;
  }
  if (i < end) {
    const int j0 = lst[i];
    const float2 r0 = *(const float2*)(src + (size_t)j0 * 128 + co);
    const float p0 = pre_scale ? pre_scale[j0] : 1.0f;
    ax0 += r0.x * p0; ay0 += r0.y * p0;
  }
  const float ps = post_scale ? post_scale[seg] : 1.0f;
  float ox = (ax0 + ax1) * ps;
  float oy = (ay0 + ay1) * ps;
  if (final_mode) {
    ox = ox > 0.f ? ox : expm1f(ox);
    oy = oy > 0.f ? oy : expm1f(oy);
  }
  *(float2*)(dst + (size_t)seg * 128 + co) = make_float2(ox, oy);
}

// ---------------- attention e2v: Xv1[v] = sum es_i*Xe1[e_i] / sum es_i ----------------
__global__ __launch_bounds__(256) void attn_pass_kernel(
    const float* __restrict__ src, float* __restrict__ dst,
    const int* __restrict__ off, const int* __restrict__ lst,
    const float* __restrict__ score, int nseg) {
  const int seg = blockIdx.x * 4 + ((int)threadIdx.x >> 6);
  const int lane = (int)threadIdx.x & 63;
  if (seg >= nseg) return;
  const int beg = off[seg];
  const int end = off[seg + 1];
  const int co = lane << 1;
  float ax = 0.f, ay = 0.f, den = 0.f;
  for (int i = beg; i < end; ++i) {
    const int e = lst[i];
    const float es = score[i];
    const float2 r = *(const float2*)(src + (size_t)e * 128 + co);
    ax += es * r.x; ay += es * r.y;
    den += es;
  }
  const float inv = (end > beg) ? 1.0f / den : 0.0f;
  *(float2*)(dst + (size_t)seg * 128 + co) = make_float2(ax * inv, ay * inv);
}

extern "C" void kernel_launch(void* const* d_in, const int* in_sizes, int n_in,
                              void* d_out, int out_size, void* d_ws, size_t ws_size,
                              hipStream_t stream) {
  const float* X      = (const float*)d_in[0];
  const int*   pair_v = (const int*)d_in[1];
  const int*   pair_e = (const int*)d_in[2];
  const int*   src_v  = (const int*)d_in[3];
  const float* W      = (const float*)d_in[4];
  const float* bias   = (const float*)d_in[5];
  const float* wsrc   = (const float*)d_in[6];
  const float* wdst   = (const float*)d_in[7];

  const int N = in_sizes[0] / 128;
  const int P = in_sizes[1];
  const int M = M_EDGES;   // fixed by problem definition (pair_e in [0, 50000))

  char* w = (char*)d_ws;
  auto alloc = [&](size_t bytes) -> char* {
    char* p = w;
    w += (bytes + 255) & ~(size_t)255;
    return p;
  };
  // ---- zero-initialized region (one memset) ----
  char* zbase = w;
  int* cnt_e = (int*)alloc((size_t)M * 4);
  int* cnt_v = (int*)alloc((size_t)N * 4);
  int* cur_e = (int*)alloc((size_t)M * 4);
  int* cur_v = (int*)alloc((size_t)N * 4);
  const size_t zbytes = (size_t)(w - zbase);
  // ---- rest of workspace ----
  int*   edge_off  = (int*)alloc((size_t)(M + 1) * 4);
  int*   vtx_off   = (int*)alloc((size_t)(N + 1) * 4);
  float* de_inv    = (float*)alloc((size_t)M * 4);
  float* dv_inv    = (float*)alloc((size_t)N * 4);
  float* dv_isqrt  = (float*)alloc((size_t)N * 4);
  float* svec      = (float*)alloc((size_t)N * 4);
  float* dvec      = (float*)alloc((size_t)N * 4);
  int*   edge_vtx  = (int*)alloc((size_t)P * 4);
  int*   vtx_edge  = (int*)alloc((size_t)P * 4);
  float* vtx_score = (float*)alloc((size_t)P * 4);
  float* bufN      = (float*)alloc((size_t)N * 128 * 4);  // H -> Hs -> Xv1
  float* bufM      = (float*)alloc((size_t)M * 128 * 4);  // Xe -> Xe1 -> Xe2

  hipMemsetAsync(zbase, 0, zbytes, stream);

  const int pb = (P + 255) / 256;
  count_kernel<<<pb, 256, 0, stream>>>(pair_e, pair_v, cnt_e, cnt_v, P);
  scan_kernel<<<1, 1024, 0, stream>>>(cnt_e, edge_off, de_inv, nullptr, M);
  scan_kernel<<<1, 1024, 0, stream>>>(cnt_v, vtx_off, dv_inv, dv_isqrt, N);
  gemm_kernel<<<(N + 31) / 32, 256, 0, stream>>>(X, W, bias, wsrc, wdst,
                                                 bufN, svec, dvec, N);
  fill_kernel<<<pb, 256, 0, stream>>>(pair_e, pair_v, src_v, edge_off, vtx_off,
                                      cur_e, cur_v, edge_vtx, vtx_edge, vtx_score,
                                      svec, dvec, P);

  const int gm = (M + 3) / 4;
  const int gn = (N + 3) / 4;
  // P1: Xe  = de_inv * sum H[v] * dv_isqrt[v]
  seg_pass_kernel<<<gm, 256, 0, stream>>>(bufN, bufM, edge_off, edge_vtx, dv_isqrt, de_inv, M, 0);
  // P2: Hs  = dv_isqrt * sum Xe[e]
  seg_pass_kernel<<<gn, 256, 0, stream>>>(bufM, bufN, vtx_off, vtx_edge, nullptr, dv_isqrt, N, 0);
  // P3: Xe1 = de_inv * sum Hs[v]
  seg_pass_kernel<<<gm, 256, 0, stream>>>(bufN, bufM, edge_off, edge_vtx, nullptr, de_inv, M, 0);
  // P4: Xv1 = softmax-weighted sum of Xe1[e]
  attn_pass_kernel<<<gn, 256, 0, stream>>>(bufM, bufN, vtx_off, vtx_edge, vtx_score, N);
  // P5: Xe2 = de_inv * sum Xv1[v]
  seg_pass_kernel<<<gm, 256, 0, stream>>>(bufN, bufM, edge_off, edge_vtx, nullptr, de_inv, M, 0);
  // P6: out = elu(dv_inv * sum Xe2[e])  -> fp32
  seg_pass_kernel<<<gn, 256, 0, stream>>>(bufM, (float*)d_out, vtx_off, vtx_edge, nullptr, dv_inv, N, 1);
}

// Round 3
// 1178.948 us; speedup vs baseline: 1.2997x; 1.2997x over previous
//
#include <hip/hip_runtime.h>
#include <math.h>

#define M_EDGES 50000
#define CHUNK 1024

// xor swizzle at float4 granularity for GEMM W staging.
__device__ __forceinline__ int swz(int k) { return ((k >> 2) & 7) << 2; }

// ---------------- degree counting ----------------
__global__ void count_kernel(const int* __restrict__ pair_e, const int* __restrict__ pair_v,
                             int* __restrict__ cnt_e, int* __restrict__ cnt_v, int P) {
  int p = blockIdx.x * blockDim.x + threadIdx.x;
  if (p >= P) return;
  atomicAdd(&cnt_e[pair_e[p]], 1);
  atomicAdd(&cnt_v[pair_v[p]], 1);
}

// ---------------- hierarchical scan, phase A: per-chunk totals ----------------
// blocks [0,CE) cover cnt_e chunks; blocks [CE,CE+CV) cover cnt_v chunks.
__global__ __launch_bounds__(1024) void blocksum_kernel(
    const int* __restrict__ cnt_e, const int* __restrict__ cnt_v,
    int* __restrict__ part, int CE, int M, int N) {
  const int b = blockIdx.x;
  const int* cnt;
  int n, chunk;
  if (b < CE) { cnt = cnt_e; n = M; chunk = b; }
  else        { cnt = cnt_v; n = N; chunk = b - CE; }
  const int i = chunk * CHUNK + (int)threadIdx.x;
  int x = (i < n) ? cnt[i] : 0;
#pragma unroll
  for (int m = 32; m >= 1; m >>= 1) x += __shfl_xor(x, m, 64);
  __shared__ int ws[16];
  if ((threadIdx.x & 63) == 0) ws[threadIdx.x >> 6] = x;
  __syncthreads();
  if (threadIdx.x == 0) {
    int t = 0;
#pragma unroll
    for (int q = 0; q < 16; ++q) t += ws[q];
    part[b] = t;
  }
}

// ---------------- phase B: exclusive-scan the chunk totals (1 block) ----------------
__global__ __launch_bounds__(256) void partscan_kernel(
    int* __restrict__ part, int CE, int CV,
    int* __restrict__ off_e, int* __restrict__ off_v, int M, int N) {
  __shared__ int sh[256];
  const int tid = (int)threadIdx.x;
  for (int s = 0; s < 2; ++s) {
    const int base = s ? CE : 0;
    const int count = s ? CV : CE;   // both <= 256
    int x = (tid < count) ? part[base + tid] : 0;
    sh[tid] = x;
    __syncthreads();
    for (int ofs = 1; ofs < 256; ofs <<= 1) {
      int v = (tid >= ofs) ? sh[tid - ofs] : 0;
      __syncthreads();
      sh[tid] += v;
      __syncthreads();
    }
    if (tid < count) part[base + tid] = sh[tid] - x;   // exclusive
    if (tid == 0) {
      const int tot = sh[count - 1];
      if (s == 0) off_e[M] = tot; else off_v[N] = tot;
    }
    __syncthreads();
  }
}

// ---------------- phase C: per-chunk local scan + apply chunk offset ----------------
__global__ __launch_bounds__(1024) void blockscan_kernel(
    const int* __restrict__ cnt_e, const int* __restrict__ cnt_v,
    const int* __restrict__ part,
    int* __restrict__ off_e, int* __restrict__ off_v,
    float* __restrict__ de_inv, float* __restrict__ dv_inv, float* __restrict__ dv_isqrt,
    int CE, int M, int N) {
  __shared__ int sh[CHUNK];
  const int b = blockIdx.x;
  const int tid = (int)threadIdx.x;
  const int* cnt;
  int n, chunk;
  int* off;
  float *i1, *i2;
  if (b < CE) { cnt = cnt_e; n = M; chunk = b;      off = off_e; i1 = de_inv; i2 = nullptr; }
  else        { cnt = cnt_v; n = N; chunk = b - CE; off = off_v; i1 = dv_inv; i2 = dv_isqrt; }
  const int i = chunk * CHUNK + tid;
  const int x = (i < n) ? cnt[i] : 0;
  sh[tid] = x;
  __syncthreads();
  for (int ofs = 1; ofs < CHUNK; ofs <<= 1) {
    int v = (tid >= ofs) ? sh[tid - ofs] : 0;
    __syncthreads();
    sh[tid] += v;
    __syncthreads();
  }
  if (i < n) {
    off[i] = part[b] + sh[tid] - x;
    const float m = (float)(x > 1 ? x : 1);
    i1[i] = 1.0f / m;
    if (i2) i2[i] = 1.0f / sqrtf(m);
  }
}

// ---------------- GEMM: H = X @ W^T + b, fused s = H.w_src, d = H.w_dst ----------------
__global__ __launch_bounds__(256) void gemm_kernel(
    const float* __restrict__ X, const float* __restrict__ W,
    const float* __restrict__ bias, const float* __restrict__ wsrc,
    const float* __restrict__ wdst,
    float* __restrict__ H, float* __restrict__ s_out, float* __restrict__ d_out,
    int N) {
  __shared__ float lw[64 * 128];   // lw[kk*128 + (c ^ swz(kk))] = W[c][half*64+kk]
  __shared__ float lx[32 * 128];   // lx[r*128 + k]
  const int tid = threadIdx.x;
  const int row0 = blockIdx.x * 32;

  for (int g = tid; g < 32 * 32; g += 256) {
    const int r = g >> 5;
    const int k4 = (g & 31) << 2;
    int rr = row0 + r;
    if (rr >= N) rr = N - 1;
    *(float4*)(lx + r * 128 + k4) = *(const float4*)(X + (size_t)rr * 128 + k4);
  }

  const int tx = tid & 31;
  const int ty = tid >> 5;
  const int c0 = tx << 2;
  const int r0 = ty << 2;
  float acc[4][4] = {};

  for (int half = 0; half < 2; ++half) {
    __syncthreads();
    for (int g = tid; g < 128 * 16; g += 256) {
      const int c = g >> 4;
      const int kk4 = (g & 15) << 2;
      const float4 v = *(const float4*)(W + (size_t)c * 128 + half * 64 + kk4);
      const int s = swz(kk4);
      lw[(kk4 + 0) * 128 + (c ^ s)] = v.x;
      lw[(kk4 + 1) * 128 + (c ^ s)] = v.y;
      lw[(kk4 + 2) * 128 + (c ^ s)] = v.z;
      lw[(kk4 + 3) * 128 + (c ^ s)] = v.w;
    }
    __syncthreads();
#pragma unroll 8
    for (int kk = 0; kk < 64; ++kk) {
      const int k = half * 64 + kk;
      const float4 wv = *(const float4*)(lw + kk * 128 + (c0 ^ swz(kk)));
      const float x0 = lx[(r0 + 0) * 128 + k];
      const float x1 = lx[(r0 + 1) * 128 + k];
      const float x2 = lx[(r0 + 2) * 128 + k];
      const float x3 = lx[(r0 + 3) * 128 + k];
      acc[0][0] += x0 * wv.x; acc[0][1] += x0 * wv.y; acc[0][2] += x0 * wv.z; acc[0][3] += x0 * wv.w;
      acc[1][0] += x1 * wv.x; acc[1][1] += x1 * wv.y; acc[1][2] += x1 * wv.z; acc[1][3] += x1 * wv.w;
      acc[2][0] += x2 * wv.x; acc[2][1] += x2 * wv.y; acc[2][2] += x2 * wv.z; acc[2][3] += x2 * wv.w;
      acc[3][0] += x3 * wv.x; acc[3][1] += x3 * wv.y; acc[3][2] += x3 * wv.z; acc[3][3] += x3 * wv.w;
    }
  }

  const float4 bv = *(const float4*)(bias + c0);
  const float4 sv = *(const float4*)(wsrc + c0);
  const float4 dv = *(const float4*)(wdst + c0);

#pragma unroll
  for (int r = 0; r < 4; ++r) {
    const int row = row0 + r0 + r;
    float4 h;
    h.x = acc[r][0] + bv.x; h.y = acc[r][1] + bv.y;
    h.z = acc[r][2] + bv.z; h.w = acc[r][3] + bv.w;
    float ps = h.x * sv.x + h.y * sv.y + h.z * sv.z + h.w * sv.w;
    float pd = h.x * dv.x + h.y * dv.y + h.z * dv.z + h.w * dv.w;
#pragma unroll
    for (int m = 16; m >= 1; m >>= 1) {
      ps += __shfl_xor(ps, m, 64);
      pd += __shfl_xor(pd, m, 64);
    }
    if (row < N) {
      *(float4*)(H + (size_t)row * 128 + c0) = h;
      if (tx == 0) { s_out[row] = ps; d_out[row] = pd; }
    }
  }
}

// ---------------- CSR fill + per-slot attention weight ----------------
// es = exp(clip(leaky_relu(s[src]+d[v], 0.2), 0.001, 5)); clip bounds exp <= 148.4
// so no max-subtraction is needed (analytically identical softmax).
__global__ void fill_kernel(const int* __restrict__ pair_e, const int* __restrict__ pair_v,
                            const int* __restrict__ src_v,
                            const int* __restrict__ edge_off, const int* __restrict__ vtx_off,
                            int* __restrict__ cur_e, int* __restrict__ cur_v,
                            int* __restrict__ edge_vtx, int* __restrict__ vtx_edge,
                            float* __restrict__ vtx_score,
                            const float* __restrict__ svec, const float* __restrict__ dvec,
                            int P) {
  int p = blockIdx.x * blockDim.x + threadIdx.x;
  if (p >= P) return;
  int e = pair_e[p], v = pair_v[p];
  int ie = edge_off[e] + atomicAdd(&cur_e[e], 1);
  edge_vtx[ie] = v;
  int iv = vtx_off[v] + atomicAdd(&cur_v[v], 1);
  vtx_edge[iv] = e;
  float sc = svec[src_v[p]] + dvec[v];
  sc = sc > 0.f ? sc : 0.2f * sc;           // leaky_relu(0.2)
  sc = fminf(fmaxf(sc, 0.001f), 5.0f);      // clip
  vtx_score[iv] = __expf(sc);
}

// ---------------- segment gather-reduce, half-wave float4 ----------------
// wave = segment; half-wave h handles lst[i+h]; 32 lanes x float4 = 128 ch.
// dst[seg] = post[seg] * sum_i pre[lst[i]] * src[lst[i]]; final_mode: ELU.
__global__ __launch_bounds__(256) void seg_pass_kernel(
    const float* __restrict__ src, float* __restrict__ dst,
    const int* __restrict__ off, const int* __restrict__ lst,
    const float* __restrict__ pre_scale, const float* __restrict__ post_scale,
    int nseg, int final_mode) {
  const int seg = blockIdx.x * 4 + ((int)threadIdx.x >> 6);
  if (seg >= nseg) return;
  const int lane = (int)threadIdx.x & 63;
  const int half = lane >> 5;
  const int co = (lane & 31) << 2;
  const int beg = off[seg];
  const int end = off[seg + 1];
  float4 acc = make_float4(0.f, 0.f, 0.f, 0.f);
  int i = beg;
  for (; i + 2 <= end; i += 2) {
    const int j = lst[i + half];
    const float4 r = *(const float4*)(src + (size_t)j * 128 + co);
    const float p = pre_scale ? pre_scale[j] : 1.0f;
    acc.x += r.x * p; acc.y += r.y * p; acc.z += r.z * p; acc.w += r.w * p;
  }
  if (i < end && half == 0) {
    const int j = lst[i];
    const float4 r = *(const float4*)(src + (size_t)j * 128 + co);
    const float p = pre_scale ? pre_scale[j] : 1.0f;
    acc.x += r.x * p; acc.y += r.y * p; acc.z += r.z * p; acc.w += r.w * p;
  }
  acc.x += __shfl_xor(acc.x, 32, 64);
  acc.y += __shfl_xor(acc.y, 32, 64);
  acc.z += __shfl_xor(acc.z, 32, 64);
  acc.w += __shfl_xor(acc.w, 32, 64);
  const float ps = post_scale ? post_scale[seg] : 1.0f;
  float4 o = make_float4(acc.x * ps, acc.y * ps, acc.z * ps, acc.w * ps);
  if (final_mode) {
    o.x = o.x > 0.f ? o.x : expm1f(o.x);
    o.y = o.y > 0.f ? o.y : expm1f(o.y);
    o.z = o.z > 0.f ? o.z : expm1f(o.z);
    o.w = o.w > 0.f ? o.w : expm1f(o.w);
  }
  if (half == 0) *(float4*)(dst + (size_t)seg * 128 + co) = o;
}

// ---------------- attention e2v: Xv1[v] = sum es_i*Xe1[e_i] / sum es_i ----------------
__global__ __launch_bounds__(256) void attn_pass_kernel(
    const float* __restrict__ src, float* __restrict__ dst,
    const int* __restrict__ off, const int* __restrict__ lst,
    const float* __restrict__ score, int nseg) {
  const int seg = blockIdx.x * 4 + ((int)threadIdx.x >> 6);
  if (seg >= nseg) return;
  const int lane = (int)threadIdx.x & 63;
  const int half = lane >> 5;
  const int co = (lane & 31) << 2;
  const int beg = off[seg];
  const int end = off[seg + 1];
  float4 acc = make_float4(0.f, 0.f, 0.f, 0.f);
  float den = 0.f;
  int i = beg;
  for (; i + 2 <= end; i += 2) {
    const int idx = i + half;
    const int e = lst[idx];
    const float es = score[idx];
    const float4 r = *(const float4*)(src + (size_t)e * 128 + co);
    acc.x += es * r.x; acc.y += es * r.y; acc.z += es * r.z; acc.w += es * r.w;
    den += es;
  }
  if (i < end && half == 0) {
    const int e = lst[i];
    const float es = score[i];
    const float4 r = *(const float4*)(src + (size_t)e * 128 + co);
    acc.x += es * r.x; acc.y += es * r.y; acc.z += es * r.z; acc.w += es * r.w;
    den += es;
  }
  acc.x += __shfl_xor(acc.x, 32, 64);
  acc.y += __shfl_xor(acc.y, 32, 64);
  acc.z += __shfl_xor(acc.z, 32, 64);
  acc.w += __shfl_xor(acc.w, 32, 64);
  den   += __shfl_xor(den,   32, 64);
  const float inv = (end > beg) ? 1.0f / den : 0.0f;
  if (half == 0)
    *(float4*)(dst + (size_t)seg * 128 + co) =
        make_float4(acc.x * inv, acc.y * inv, acc.z * inv, acc.w * inv);
}

extern "C" void kernel_launch(void* const* d_in, const int* in_sizes, int n_in,
                              void* d_out, int out_size, void* d_ws, size_t ws_size,
                              hipStream_t stream) {
  const float* X      = (const float*)d_in[0];
  const int*   pair_v = (const int*)d_in[1];
  const int*   pair_e = (const int*)d_in[2];
  const int*   src_v  = (const int*)d_in[3];
  const float* W      = (const float*)d_in[4];
  const float* bias   = (const float*)d_in[5];
  const float* wsrc   = (const float*)d_in[6];
  const float* wdst   = (const float*)d_in[7];

  const int N = in_sizes[0] / 128;
  const int P = in_sizes[1];
  const int M = M_EDGES;   // fixed by problem definition (pair_e in [0, 50000))
  const int CE = (M + CHUNK - 1) / CHUNK;   // 49  (<=256 for partscan)
  const int CV = (N + CHUNK - 1) / CHUNK;   // 98  (<=256 for partscan)

  char* w = (char*)d_ws;
  auto alloc = [&](size_t bytes) -> char* {
    char* p = w;
    w += (bytes + 255) & ~(size_t)255;
    return p;
  };
  // ---- zero-initialized region (one memset) ----
  char* zbase = w;
  int* cnt_e = (int*)alloc((size_t)M * 4);
  int* cnt_v = (int*)alloc((size_t)N * 4);
  int* cur_e = (int*)alloc((size_t)M * 4);
  int* cur_v = (int*)alloc((size_t)N * 4);
  const size_t zbytes = (size_t)(w - zbase);
  // ---- rest of workspace ----
  int*   part      = (int*)alloc((size_t)(CE + CV) * 4);
  int*   edge_off  = (int*)alloc((size_t)(M + 1) * 4);
  int*   vtx_off   = (int*)alloc((size_t)(N + 1) * 4);
  float* de_inv    = (float*)alloc((size_t)M * 4);
  float* dv_inv    = (float*)alloc((size_t)N * 4);
  float* dv_isqrt  = (float*)alloc((size_t)N * 4);
  float* svec      = (float*)alloc((size_t)N * 4);
  float* dvec      = (float*)alloc((size_t)N * 4);
  int*   edge_vtx  = (int*)alloc((size_t)P * 4);
  int*   vtx_edge  = (int*)alloc((size_t)P * 4);
  float* vtx_score = (float*)alloc((size_t)P * 4);
  float* bufN      = (float*)alloc((size_t)N * 128 * 4);  // H -> Hs -> Xv1
  float* bufM      = (float*)alloc((size_t)M * 128 * 4);  // Xe -> Xe1 -> Xe2

  hipMemsetAsync(zbase, 0, zbytes, stream);

  const int pb = (P + 255) / 256;
  count_kernel<<<pb, 256, 0, stream>>>(pair_e, pair_v, cnt_e, cnt_v, P);
  blocksum_kernel<<<CE + CV, 1024, 0, stream>>>(cnt_e, cnt_v, part, CE, M, N);
  partscan_kernel<<<1, 256, 0, stream>>>(part, CE, CV, edge_off, vtx_off, M, N);
  blockscan_kernel<<<CE + CV, 1024, 0, stream>>>(cnt_e, cnt_v, part, edge_off, vtx_off,
                                                 de_inv, dv_inv, dv_isqrt, CE, M, N);
  gemm_kernel<<<(N + 31) / 32, 256, 0, stream>>>(X, W, bias, wsrc, wdst,
                                                 bufN, svec, dvec, N);
  fill_kernel<<<pb, 256, 0, stream>>>(pair_e, pair_v, src_v, edge_off, vtx_off,
                                      cur_e, cur_v, edge_vtx, vtx_edge, vtx_score,
                                      svec, dvec, P);

  const int gm = (M + 3) / 4;
  const int gn = (N + 3) / 4;
  // P1: Xe  = de_inv * sum H[v] * dv_isqrt[v]
  seg_pass_kernel<<<gm, 256, 0, stream>>>(bufN, bufM, edge_off, edge_vtx, dv_isqrt, de_inv, M, 0);
  // P2: Hs  = dv_isqrt * sum Xe[e]
  seg_pass_kernel<<<gn, 256, 0, stream>>>(bufM, bufN, vtx_off, vtx_edge, nullptr, dv_isqrt, N, 0);
  // P3: Xe1 = de_inv * sum Hs[v]
  seg_pass_kernel<<<gm, 256, 0, stream>>>(bufN, bufM, edge_off, edge_vtx, nullptr, de_inv, M, 0);
  // P4: Xv1 = softmax-weighted sum of Xe1[e]
  attn_pass_kernel<<<gn, 256, 0, stream>>>(bufM, bufN, vtx_off, vtx_edge, vtx_score, N);
  // P5: Xe2 = de_inv * sum Xv1[v]
  seg_pass_kernel<<<gm, 256, 0, stream>>>(bufN, bufM, edge_off, edge_vtx, nullptr, de_inv, M, 0);
  // P6: out = elu(dv_inv * sum Xe2[e])  -> fp32
  seg_pass_kernel<<<gn, 256, 0, stream>>>(bufM, (float*)d_out, vtx_off, vtx_edge, nullptr, dv_inv, N, 1);
}

// Round 4
// 837.644 us; speedup vs baseline: 1.8292x; 1.4075x over previous
//
#include <hip/hip_runtime.h>
#include <math.h>

#define M_EDGES 50000
#define CHUNK 1024

typedef unsigned int u32;
typedef unsigned short u16;

__device__ __forceinline__ float bflo(u32 u) { return __uint_as_float(u << 16); }
__device__ __forceinline__ float bfhi(u32 u) { return __uint_as_float(u & 0xffff0000u); }
__device__ __forceinline__ u32 packbf(float x, float y) {   // RNE both halves
  u32 a = __float_as_uint(x); a += 0x7fffu + ((a >> 16) & 1u);
  u32 b = __float_as_uint(y); b += 0x7fffu + ((b >> 16) & 1u);
  return (a >> 16) | (b & 0xffff0000u);
}
// xor swizzle at float4 granularity for GEMM W staging.
__device__ __forceinline__ int swz(int k) { return ((k >> 2) & 7) << 2; }

// ---------------- degree counting ----------------
__global__ void count_kernel(const int* __restrict__ pair_e, const int* __restrict__ pair_v,
                             int* __restrict__ cnt_e, int* __restrict__ cnt_v, int P) {
  int p = blockIdx.x * blockDim.x + threadIdx.x;
  if (p >= P) return;
  atomicAdd(&cnt_e[pair_e[p]], 1);
  atomicAdd(&cnt_v[pair_v[p]], 1);
}

// ---------------- hierarchical scan, phase A: per-chunk totals ----------------
__global__ __launch_bounds__(1024) void blocksum_kernel(
    const int* __restrict__ cnt_e, const int* __restrict__ cnt_v,
    int* __restrict__ part, int CE, int M, int N) {
  const int b = blockIdx.x;
  const int* cnt;
  int n, chunk;
  if (b < CE) { cnt = cnt_e; n = M; chunk = b; }
  else        { cnt = cnt_v; n = N; chunk = b - CE; }
  const int i = chunk * CHUNK + (int)threadIdx.x;
  int x = (i < n) ? cnt[i] : 0;
#pragma unroll
  for (int m = 32; m >= 1; m >>= 1) x += __shfl_xor(x, m, 64);
  __shared__ int ws[16];
  if ((threadIdx.x & 63) == 0) ws[threadIdx.x >> 6] = x;
  __syncthreads();
  if (threadIdx.x == 0) {
    int t = 0;
#pragma unroll
    for (int q = 0; q < 16; ++q) t += ws[q];
    part[b] = t;
  }
}

// ---------------- phase B: exclusive-scan chunk totals (1 block) ----------------
__global__ __launch_bounds__(256) void partscan_kernel(
    int* __restrict__ part, int CE, int CV,
    int* __restrict__ off_e, int* __restrict__ off_v, int M, int N) {
  __shared__ int sh[256];
  const int tid = (int)threadIdx.x;
  for (int s = 0; s < 2; ++s) {
    const int base = s ? CE : 0;
    const int count = s ? CV : CE;   // both <= 256
    int x = (tid < count) ? part[base + tid] : 0;
    sh[tid] = x;
    __syncthreads();
    for (int ofs = 1; ofs < 256; ofs <<= 1) {
      int v = (tid >= ofs) ? sh[tid - ofs] : 0;
      __syncthreads();
      sh[tid] += v;
      __syncthreads();
    }
    if (tid < count) part[base + tid] = sh[tid] - x;   // exclusive
    if (tid == 0) {
      const int tot = sh[count - 1];
      if (s == 0) off_e[M] = tot; else off_v[N] = tot;
    }
    __syncthreads();
  }
}

// ---------------- phase C: local scan + offsets + cursors + inv-degrees ----------------
__global__ __launch_bounds__(1024) void blockscan_kernel(
    const int* __restrict__ cnt_e, const int* __restrict__ cnt_v,
    const int* __restrict__ part,
    int* __restrict__ off_e, int* __restrict__ off_v,
    int* __restrict__ cur_e, int* __restrict__ cur_v,
    float* __restrict__ de_inv, float* __restrict__ dv_inv, float* __restrict__ dv_isqrt,
    int CE, int M, int N) {
  __shared__ int sh[CHUNK];
  const int b = blockIdx.x;
  const int tid = (int)threadIdx.x;
  const int* cnt;
  int n, chunk;
  int *off, *cur;
  float *i1, *i2;
  if (b < CE) { cnt = cnt_e; n = M; chunk = b;      off = off_e; cur = cur_e; i1 = de_inv; i2 = nullptr; }
  else        { cnt = cnt_v; n = N; chunk = b - CE; off = off_v; cur = cur_v; i1 = dv_inv; i2 = dv_isqrt; }
  const int i = chunk * CHUNK + tid;
  const int x = (i < n) ? cnt[i] : 0;
  sh[tid] = x;
  __syncthreads();
  for (int ofs = 1; ofs < CHUNK; ofs <<= 1) {
    int v = (tid >= ofs) ? sh[tid - ofs] : 0;
    __syncthreads();
    sh[tid] += v;
    __syncthreads();
  }
  if (i < n) {
    const int o = part[b] + sh[tid] - x;
    off[i] = o;
    cur[i] = o;              // cursor pre-initialized to offset
    const float m = (float)(x > 1 ? x : 1);
    i1[i] = 1.0f / m;
    if (i2) i2[i] = 1.0f / sqrtf(m);
  }
}

// ---------------- GEMM: H = X@W^T + b; fused s=H.w_src, d=H.w_dst ----------------
// stores Hs = H * dv_isqrt[row] as packed bf16 (H only feeds P1, which needs that scale).
__global__ __launch_bounds__(256) void gemm_kernel(
    const float* __restrict__ X, const float* __restrict__ W,
    const float* __restrict__ bias, const float* __restrict__ wsrc,
    const float* __restrict__ wdst, const float* __restrict__ dv_isqrt,
    u16* __restrict__ Hb, float* __restrict__ s_out, float* __restrict__ d_out,
    int N) {
  __shared__ float lw[64 * 128];   // lw[kk*128 + (c ^ swz(kk))] = W[c][half*64+kk]
  __shared__ float lx[32 * 128];   // lx[r*128 + k]
  const int tid = threadIdx.x;
  const int row0 = blockIdx.x * 32;

  for (int g = tid; g < 32 * 32; g += 256) {
    const int r = g >> 5;
    const int k4 = (g & 31) << 2;
    int rr = row0 + r;
    if (rr >= N) rr = N - 1;
    *(float4*)(lx + r * 128 + k4) = *(const float4*)(X + (size_t)rr * 128 + k4);
  }

  const int tx = tid & 31;
  const int ty = tid >> 5;
  const int c0 = tx << 2;
  const int r0 = ty << 2;
  float acc[4][4] = {};

  for (int half = 0; half < 2; ++half) {
    __syncthreads();
    for (int g = tid; g < 128 * 16; g += 256) {
      const int c = g >> 4;
      const int kk4 = (g & 15) << 2;
      const float4 v = *(const float4*)(W + (size_t)c * 128 + half * 64 + kk4);
      const int s = swz(kk4);
      lw[(kk4 + 0) * 128 + (c ^ s)] = v.x;
      lw[(kk4 + 1) * 128 + (c ^ s)] = v.y;
      lw[(kk4 + 2) * 128 + (c ^ s)] = v.z;
      lw[(kk4 + 3) * 128 + (c ^ s)] = v.w;
    }
    __syncthreads();
#pragma unroll 8
    for (int kk = 0; kk < 64; ++kk) {
      const int k = half * 64 + kk;
      const float4 wv = *(const float4*)(lw + kk * 128 + (c0 ^ swz(kk)));
      const float x0 = lx[(r0 + 0) * 128 + k];
      const float x1 = lx[(r0 + 1) * 128 + k];
      const float x2 = lx[(r0 + 2) * 128 + k];
      const float x3 = lx[(r0 + 3) * 128 + k];
      acc[0][0] += x0 * wv.x; acc[0][1] += x0 * wv.y; acc[0][2] += x0 * wv.z; acc[0][3] += x0 * wv.w;
      acc[1][0] += x1 * wv.x; acc[1][1] += x1 * wv.y; acc[1][2] += x1 * wv.z; acc[1][3] += x1 * wv.w;
      acc[2][0] += x2 * wv.x; acc[2][1] += x2 * wv.y; acc[2][2] += x2 * wv.z; acc[2][3] += x2 * wv.w;
      acc[3][0] += x3 * wv.x; acc[3][1] += x3 * wv.y; acc[3][2] += x3 * wv.z; acc[3][3] += x3 * wv.w;
    }
  }

  const float4 bv = *(const float4*)(bias + c0);
  const float4 sv = *(const float4*)(wsrc + c0);
  const float4 dv = *(const float4*)(wdst + c0);

#pragma unroll
  for (int r = 0; r < 4; ++r) {
    const int row = row0 + r0 + r;
    float4 h;
    h.x = acc[r][0] + bv.x; h.y = acc[r][1] + bv.y;
    h.z = acc[r][2] + bv.z; h.w = acc[r][3] + bv.w;
    float ps = h.x * sv.x + h.y * sv.y + h.z * sv.z + h.w * sv.w;
    float pd = h.x * dv.x + h.y * dv.y + h.z * dv.z + h.w * dv.w;
#pragma unroll
    for (int m = 16; m >= 1; m >>= 1) {
      ps += __shfl_xor(ps, m, 64);
      pd += __shfl_xor(pd, m, 64);
    }
    if (row < N) {
      const float sc = dv_isqrt[row];
      uint2 pk;
      pk.x = packbf(h.x * sc, h.y * sc);
      pk.y = packbf(h.z * sc, h.w * sc);
      *(uint2*)(Hb + (size_t)row * 128 + c0) = pk;
      if (tx == 0) { s_out[row] = ps; d_out[row] = pd; }
    }
  }
}

// ---------------- CSR fill + per-slot attention weight ----------------
// es = exp(clip(leaky_relu(s[src]+d[v], 0.2), 0.001, 5)); clip bounds exp<=148.4 so
// softmax needs no max-subtraction (analytically identical). (e,es) packed in one int2.
__global__ void fill_kernel(const int* __restrict__ pair_e, const int* __restrict__ pair_v,
                            const int* __restrict__ src_v,
                            int* __restrict__ cur_e, int* __restrict__ cur_v,
                            int* __restrict__ edge_vtx, int2* __restrict__ vtx_es,
                            const float* __restrict__ svec, const float* __restrict__ dvec,
                            int P) {
  int p = blockIdx.x * blockDim.x + threadIdx.x;
  if (p >= P) return;
  int e = pair_e[p], v = pair_v[p];
  int ie = atomicAdd(&cur_e[e], 1);
  edge_vtx[ie] = v;
  int iv = atomicAdd(&cur_v[v], 1);
  float sc = svec[src_v[p]] + dvec[v];
  sc = sc > 0.f ? sc : 0.2f * sc;           // leaky_relu(0.2)
  sc = fminf(fmaxf(sc, 0.001f), 5.0f);      // clip
  vtx_es[iv] = make_int2(e, __float_as_int(__expf(sc)));
}

#define ACC8(r, p)                                         \
  a[0] += bflo((r).x) * (p); a[1] += bfhi((r).x) * (p);    \
  a[2] += bflo((r).y) * (p); a[3] += bfhi((r).y) * (p);    \
  a[4] += bflo((r).z) * (p); a[5] += bfhi((r).z) * (p);    \
  a[6] += bflo((r).w) * (p); a[7] += bfhi((r).w) * (p);

// ---------------- segment gather-reduce, quarter-wave, bf16 rows ----------------
// wave = segment; quarter q handles lst[i+q]; 16 lanes x uint4 (8 bf16 ch) = 256B row.
// dst[seg] = post[seg] * sum_i pre[lst[i]] * src[lst[i]].  lstride: ints per list entry.
// final_mode: ELU + fp32 output (512B rows).
__global__ __launch_bounds__(256) void seg_pass_kernel(
    const u16* __restrict__ src, void* __restrict__ dst,
    const int* __restrict__ off, const int* __restrict__ lst, int lstride,
    const float* __restrict__ pre_scale, const float* __restrict__ post_scale,
    int nseg, int final_mode) {
  const int seg = blockIdx.x * 4 + ((int)threadIdx.x >> 6);
  if (seg >= nseg) return;
  const int lane = (int)threadIdx.x & 63;
  const int q = lane >> 4;
  const int cl = lane & 15;
  const int beg = off[seg], end = off[seg + 1];
  float a[8] = {};
  int i = beg;
  for (; i + 4 <= end; i += 4) {
    const int j = lst[(size_t)(i + q) * lstride];
    const uint4 r = *(const uint4*)(src + (size_t)j * 128 + cl * 8);
    const float p = pre_scale ? pre_scale[j] : 1.0f;
    ACC8(r, p)
  }
  if (i + q < end) {
    const int j = lst[(size_t)(i + q) * lstride];
    const uint4 r = *(const uint4*)(src + (size_t)j * 128 + cl * 8);
    const float p = pre_scale ? pre_scale[j] : 1.0f;
    ACC8(r, p)
  }
#pragma unroll
  for (int k = 0; k < 8; ++k) {
    a[k] += __shfl_xor(a[k], 16, 64);
    a[k] += __shfl_xor(a[k], 32, 64);
  }
  const float ps = post_scale ? post_scale[seg] : 1.0f;
#pragma unroll
  for (int k = 0; k < 8; ++k) a[k] *= ps;
  if (q != 0) return;
  if (final_mode) {
#pragma unroll
    for (int k = 0; k < 8; ++k) a[k] = a[k] > 0.f ? a[k] : expm1f(a[k]);
    float* o = (float*)dst + (size_t)seg * 128 + cl * 8;
    *(float4*)(o + 0) = make_float4(a[0], a[1], a[2], a[3]);
    *(float4*)(o + 4) = make_float4(a[4], a[5], a[6], a[7]);
  } else {
    uint4 pk;
    pk.x = packbf(a[0], a[1]); pk.y = packbf(a[2], a[3]);
    pk.z = packbf(a[4], a[5]); pk.w = packbf(a[6], a[7]);
    *(uint4*)((u16*)dst + (size_t)seg * 128 + cl * 8) = pk;
  }
}

// ---------------- attention e2v: Xv1[v] = sum es_i*Xe1[e_i] / sum es_i ----------------
__global__ __launch_bounds__(256) void attn_pass_kernel(
    const u16* __restrict__ src, u16* __restrict__ dst,
    const int* __restrict__ off, const int2* __restrict__ lst_es, int nseg) {
  const int seg = blockIdx.x * 4 + ((int)threadIdx.x >> 6);
  if (seg >= nseg) return;
  const int lane = (int)threadIdx.x & 63;
  const int q = lane >> 4;
  const int cl = lane & 15;
  const int beg = off[seg], end = off[seg + 1];
  float a[8] = {};
  float den = 0.f;
  int i = beg;
  for (; i + 4 <= end; i += 4) {
    const int2 ee = lst_es[i + q];
    const float es = __int_as_float(ee.y);
    const uint4 r = *(const uint4*)(src + (size_t)ee.x * 128 + cl * 8);
    ACC8(r, es)
    den += es;
  }
  if (i + q < end) {
    const int2 ee = lst_es[i + q];
    const float es = __int_as_float(ee.y);
    const uint4 r = *(const uint4*)(src + (size_t)ee.x * 128 + cl * 8);
    ACC8(r, es)
    den += es;
  }
#pragma unroll
  for (int k = 0; k < 8; ++k) {
    a[k] += __shfl_xor(a[k], 16, 64);
    a[k] += __shfl_xor(a[k], 32, 64);
  }
  den += __shfl_xor(den, 16, 64);
  den += __shfl_xor(den, 32, 64);
  const float inv = (end > beg) ? 1.0f / den : 0.0f;
  if (q != 0) return;
  uint4 pk;
  pk.x = packbf(a[0] * inv, a[1] * inv); pk.y = packbf(a[2] * inv, a[3] * inv);
  pk.z = packbf(a[4] * inv, a[5] * inv); pk.w = packbf(a[6] * inv, a[7] * inv);
  *(uint4*)(dst + (size_t)seg * 128 + cl * 8) = pk;
}

extern "C" void kernel_launch(void* const* d_in, const int* in_sizes, int n_in,
                              void* d_out, int out_size, void* d_ws, size_t ws_size,
                              hipStream_t stream) {
  const float* X      = (const float*)d_in[0];
  const int*   pair_v = (const int*)d_in[1];
  const int*   pair_e = (const int*)d_in[2];
  const int*   src_v  = (const int*)d_in[3];
  const float* W      = (const float*)d_in[4];
  const float* bias   = (const float*)d_in[5];
  const float* wsrc   = (const float*)d_in[6];
  const float* wdst   = (const float*)d_in[7];

  const int N = in_sizes[0] / 128;
  const int P = in_sizes[1];
  const int M = M_EDGES;   // fixed by problem definition (pair_e in [0, 50000))
  const int CE = (M + CHUNK - 1) / CHUNK;   // <=256 for partscan
  const int CV = (N + CHUNK - 1) / CHUNK;   // <=256 for partscan

  char* w = (char*)d_ws;
  auto alloc = [&](size_t bytes) -> char* {
    char* p = w;
    w += (bytes + 255) & ~(size_t)255;
    return p;
  };
  // ---- zero-initialized region (one memset: counts only) ----
  char* zbase = w;
  int* cnt_e = (int*)alloc((size_t)M * 4);
  int* cnt_v = (int*)alloc((size_t)N * 4);
  const size_t zbytes = (size_t)(w - zbase);
  // ---- rest of workspace ----
  int*   cur_e     = (int*)alloc((size_t)M * 4);
  int*   cur_v     = (int*)alloc((size_t)N * 4);
  int*   part      = (int*)alloc((size_t)(CE + CV) * 4);
  int*   edge_off  = (int*)alloc((size_t)(M + 1) * 4);
  int*   vtx_off   = (int*)alloc((size_t)(N + 1) * 4);
  float* de_inv    = (float*)alloc((size_t)M * 4);
  float* dv_inv    = (float*)alloc((size_t)N * 4);
  float* dv_isqrt  = (float*)alloc((size_t)N * 4);
  float* svec      = (float*)alloc((size_t)N * 4);
  float* dvec      = (float*)alloc((size_t)N * 4);
  int*   edge_vtx  = (int*)alloc((size_t)P * 4);
  int2*  vtx_es    = (int2*)alloc((size_t)P * 8);
  u16*   bufN      = (u16*)alloc((size_t)N * 128 * 2);  // Hs -> Hs2 -> Xv1 (bf16)
  u16*   bufM      = (u16*)alloc((size_t)M * 128 * 2);  // Xe -> Xe1 -> Xe2 (bf16)

  hipMemsetAsync(zbase, 0, zbytes, stream);

  const int pb = (P + 255) / 256;
  count_kernel<<<pb, 256, 0, stream>>>(pair_e, pair_v, cnt_e, cnt_v, P);
  blocksum_kernel<<<CE + CV, 1024, 0, stream>>>(cnt_e, cnt_v, part, CE, M, N);
  partscan_kernel<<<1, 256, 0, stream>>>(part, CE, CV, edge_off, vtx_off, M, N);
  blockscan_kernel<<<CE + CV, 1024, 0, stream>>>(cnt_e, cnt_v, part, edge_off, vtx_off,
                                                 cur_e, cur_v, de_inv, dv_inv, dv_isqrt,
                                                 CE, M, N);
  gemm_kernel<<<(N + 31) / 32, 256, 0, stream>>>(X, W, bias, wsrc, wdst, dv_isqrt,
                                                 bufN, svec, dvec, N);
  fill_kernel<<<pb, 256, 0, stream>>>(pair_e, pair_v, src_v, cur_e, cur_v,
                                      edge_vtx, vtx_es, svec, dvec, P);

  const int gm = (M + 3) / 4;
  const int gn = (N + 3) / 4;
  // P1: Xe  = de_inv * sum Hs[v]          (dv_isqrt folded into Hs at GEMM)
  seg_pass_kernel<<<gm, 256, 0, stream>>>(bufN, bufM, edge_off, edge_vtx, 1, nullptr, de_inv, M, 0);
  // P2: Hs2 = dv_isqrt * sum Xe[e]
  seg_pass_kernel<<<gn, 256, 0, stream>>>(bufM, bufN, vtx_off, (const int*)vtx_es, 2, nullptr, dv_isqrt, N, 0);
  // P3: Xe1 = de_inv * sum Hs2[v]
  seg_pass_kernel<<<gm, 256, 0, stream>>>(bufN, bufM, edge_off, edge_vtx, 1, nullptr, de_inv, M, 0);
  // P4: Xv1 = softmax-weighted sum of Xe1[e]
  attn_pass_kernel<<<gn, 256, 0, stream>>>(bufM, bufN, vtx_off, vtx_es, N);
  // P5: Xe2 = de_inv * sum Xv1[v]
  seg_pass_kernel<<<gm, 256, 0, stream>>>(bufN, bufM, edge_off, edge_vtx, 1, nullptr, de_inv, M, 0);
  // P6: out = elu(dv_inv * sum Xe2[e])  -> fp32
  seg_pass_kernel<<<gn, 256, 0, stream>>>(bufM, d_out, vtx_off, (const int*)vtx_es, 2, nullptr, dv_inv, N, 1);
}